// Round 10
// baseline (128.944 us; speedup 1.0000x reference)
//
#include <hip/hip_runtime.h>

typedef __attribute__((ext_vector_type(8))) short short8;
typedef __attribute__((ext_vector_type(4))) float f32x4;
typedef __attribute__((ext_vector_type(4))) unsigned short u16x4;

#define MFMA16(a, b, c) __builtin_amdgcn_mfma_f32_16x16x32_bf16(a, b, c, 0, 0, 0)

// global_load_lds: per-lane 16B from global -> wave-uniform LDS base + lane*16
#define GLD16(gp, lp) __builtin_amdgcn_global_load_lds( \
    (const __attribute__((address_space(1))) unsigned int*)(gp), \
    (__attribute__((address_space(3))) unsigned int*)(lp), 16, 0, 0)

__device__ __forceinline__ unsigned short f2bf(float f) {
    union { float f; unsigned int u; } v; v.f = f;
    unsigned int r = (v.u + 0x7fffu + ((v.u >> 16) & 1u)) >> 16;
    return (unsigned short)r;
}

// Stage 8 fp32 elems (2 float4) -> 8 bf16 -> one ds_write_b128 at the slot
// GLD16 would have used (elem offset lane*8).  Bit-identical to the old
// convertk + GLD16 path.
__device__ __forceinline__ void stage_fp32(const float* __restrict__ gp,
                                           unsigned short* lp, int lane) {
    float4 a = *(const float4*)gp;
    float4 b = *(const float4*)(gp + 4);
    short8 pk;
    pk[0] = (short)f2bf(a.x); pk[1] = (short)f2bf(a.y);
    pk[2] = (short)f2bf(a.z); pk[3] = (short)f2bf(a.w);
    pk[4] = (short)f2bf(b.x); pk[5] = (short)f2bf(b.y);
    pk[6] = (short)f2bf(b.z); pk[7] = (short)f2bf(b.w);
    *(short8*)(lp + lane * 8) = pk;
}

// ---------------------------------------------------------------------------
// Kernel 1: QKV GEMM, 64x128 tiles, BK=64, fused fp32->bf16 convert in
// staging (R10: convertk dispatch eliminated), fused RoPE epilogue.
// LDS group = 16 rows x 32 cols (512 elems); swizzle identical to GLD16 path.
// ---------------------------------------------------------------------------
__global__ __launch_bounds__(256) void gemm_qkv(
    const float* __restrict__ x, const float* __restrict__ Wq,
    const float* __restrict__ Wk, const float* __restrict__ Wv,
    const float* __restrict__ bq, const float* __restrict__ bk,
    const float* __restrict__ bv,
    unsigned short* __restrict__ qb, unsigned short* __restrict__ kb,
    unsigned short* __restrict__ vT)
{
    const int z = blockIdx.z;
    const float* Wz = (z == 0) ? Wq : (z == 1) ? Wk : Wv;
    const int n0 = blockIdx.x * 128, m0 = blockIdx.y * 64;
    __shared__ unsigned short Al[8 * 512];    // 8 KB
    __shared__ unsigned short Bl[16 * 512];   // 16 KB
    const int t = threadIdx.x;
    const int lane = t & 63, w = t >> 6;
    const int wrow = (w >> 1) * 32, wcol = (w & 1) * 64;
    const int quad = lane >> 4, n16 = lane & 15;
    const int rA = lane >> 2;
    const int cG = (((lane & 3) ^ ((rA >> 1) & 3))) * 8;
    const int slotq = (quad ^ ((n16 >> 1) & 3)) * 8;
    f32x4 acc[2][4] = {};
    for (int k0 = 0; k0 < 512; k0 += 64) {
        __syncthreads();
        #pragma unroll
        for (int p = 0; p < 2; p++)
            stage_fp32(&x[(m0 + w * 16 + rA) * 512 + k0 + p * 32 + cG],
                       &Al[(w * 2 + p) * 512], lane);
        #pragma unroll
        for (int j = 0; j < 4; j++)
            stage_fp32(&Wz[(n0 + w * 32 + (j >> 1) * 16 + rA) * 512 + k0 + (j & 1) * 32 + cG],
                       &Bl[(w * 4 + j) * 512], lane);
        __syncthreads();
        short8 af[2][2], bfr[4][2];
        #pragma unroll
        for (int mi = 0; mi < 2; mi++)
            #pragma unroll
            for (int p = 0; p < 2; p++)
                af[mi][p] = *(const short8*)&Al[((2 * (w >> 1) + mi) * 2 + p) * 512 + n16 * 32 + slotq];
        #pragma unroll
        for (int ni = 0; ni < 4; ni++)
            #pragma unroll
            for (int p = 0; p < 2; p++)
                bfr[ni][p] = *(const short8*)&Bl[((4 * (w & 1) + ni) * 2 + p) * 512 + n16 * 32 + slotq];
        #pragma unroll
        for (int p = 0; p < 2; p++)
            #pragma unroll
            for (int mi = 0; mi < 2; mi++)
                #pragma unroll
                for (int ni = 0; ni < 4; ni++)
                    acc[mi][ni] = MFMA16(af[mi][p], bfr[ni][p], acc[mi][ni]);
    }
    const float* bias_p = (z == 0) ? bq : (z == 1) ? bk : bv;
    unsigned short* dst01 = (z == 0) ? qb : kb;
    #pragma unroll
    for (int mi = 0; mi < 2; mi++) {
        #pragma unroll
        for (int ni = 0; ni < 4; ni++) {
            const int n = n0 + wcol + ni * 16 + n16;
            const int mb = m0 + wrow + mi * 16 + quad * 4;
            const float bias = bias_p[n];
            const int h = n >> 6;
            const int e_lo = ni * 16 + n16;
            f32x4 v = acc[mi][ni];
            if (z < 2) {
                float vr[4];
                #pragma unroll
                for (int r = 0; r < 4; r++) vr[r] = v[r] + bias;
                if (ni < 2) {   // e < 32: RoPE
                    const int j = e_lo >> 1;
                    const float theta = exp2f(-(float)j * 0.8304820237218405f);
                    #pragma unroll
                    for (int r = 0; r < 4; r++) {
                        int l = (mb + r) & 2047;
                        float s, c;
                        __sincosf((float)l * theta, &s, &c);
                        float p = __shfl_xor(vr[r], 1);
                        vr[r] = (e_lo & 1) ? (c * vr[r] + s * p) : (c * vr[r] - s * p);
                    }
                }
                #pragma unroll
                for (int r = 0; r < 4; r++) {
                    int m = mb + r, b = m >> 11, l = m & 2047;
                    dst01[((b * 8 + h) * 2048 + l) * 64 + e_lo] = f2bf(vr[r]);
                }
            } else {
                int b = mb >> 11, l = mb & 2047;
                u16x4 pk;
                #pragma unroll
                for (int r = 0; r < 4; r++) pk[r] = f2bf(v[r] + bias);
                *(u16x4*)&vT[((b * 8 + h) * 64 + e_lo) * 2048 + l] = pk;
            }
        }
    }
}

// ---------------------------------------------------------------------------
// Kernel 2: attention. grid (63, 8, 2), single chunk per block.
// K/V staged once per block into LDS (waves 0-1 K, 2-3 V), XOR swizzle.
// (unchanged from R9)
// ---------------------------------------------------------------------------
__global__ __launch_bounds__(256) void attn_all(
    const unsigned short* __restrict__ qb, const unsigned short* __restrict__ kb,
    const unsigned short* __restrict__ vT, const float* __restrict__ bias_emb,
    unsigned short* __restrict__ voutb,
    float* __restrict__ Opart, float* __restrict__ Mp, float* __restrict__ Lp)
{
    const int xid = blockIdx.x, h = blockIdx.y, b = blockIdx.z;
    const int t = threadIdx.x, lane = t & 63, w = t >> 6;
    const int quad = lane >> 4, n16 = lane & 15;
    const int bh = b * 8 + h;
    __shared__ unsigned short Kl[64 * 64];
    __shared__ unsigned short Vl[64 * 64];
    __shared__ unsigned short Pl[4 * 1280];
    unsigned short* Pw = &Pl[w * 1280];
    const int qoff = bh * 2048 * 64;
    const float scale = 0.125f;
    const bool isSplit = (xid >= 31);
    const int var = isSplit ? 31 : xid;
    const int chunk = isSplit ? (xid - 31) : xid;
    const bool causal = (chunk == var);
    const float biasv = causal ? bias_emb[8 + h] : bias_emb[h];
    const int m0 = var * 64 + w * 16;
    const int j0 = chunk * 64;
    const int iloc = w * 16 + quad * 4;

    {
        const int half = (w & 1) * 32;
        const int rl = lane >> 3;
        const int gblk = ((lane & 7) ^ (rl & 7)) * 8;
        if (w < 2) {
            #pragma unroll
            for (int n = 0; n < 4; n++) {
                const int row = half + n * 8 + rl;
                GLD16(&kb[qoff + (j0 + row) * 64 + gblk], &Kl[(half + n * 8) * 64]);
            }
        } else {
            #pragma unroll
            for (int n = 0; n < 4; n++) {
                const int row = half + n * 8 + rl;
                GLD16(&vT[(bh * 64 + row) * 2048 + j0 + gblk], &Vl[(half + n * 8) * 64]);
            }
        }
    }
    short8 aq0 = *(const short8*)&qb[qoff + (m0 + n16) * 64 + quad * 8];
    short8 aq1 = *(const short8*)&qb[qoff + (m0 + n16) * 64 + 32 + quad * 8];
    __syncthreads();

    const int sl0 = (quad ^ (n16 & 7)) * 8;
    const int sl1 = (((quad + 4) ^ (n16 & 7))) * 8;
    f32x4 sc[4];
    #pragma unroll
    for (int nt = 0; nt < 4; nt++) {
        short8 k0f = *(const short8*)&Kl[(nt * 16 + n16) * 64 + sl0];
        short8 k1f = *(const short8*)&Kl[(nt * 16 + n16) * 64 + sl1];
        f32x4 s = {};
        s = MFMA16(aq0, k0f, s);
        s = MFMA16(aq1, k1f, s);
        sc[nt] = s;
    }
    float zl[4][4];
    #pragma unroll
    for (int nt = 0; nt < 4; nt++) {
        int jloc = nt * 16 + n16;
        #pragma unroll
        for (int r = 0; r < 4; r++) {
            float zz = scale * (sc[nt][r] + biasv);
            if (causal && jloc > iloc + r) zz = -1e30f;
            zl[nt][r] = zz;
        }
    }
    float cm[4], rsum[4], pr[4][4];
    #pragma unroll
    for (int r = 0; r < 4; r++)
        cm[r] = fmaxf(fmaxf(zl[0][r], zl[1][r]), fmaxf(zl[2][r], zl[3][r]));
    #pragma unroll
    for (int off = 1; off < 16; off <<= 1)
        #pragma unroll
        for (int r = 0; r < 4; r++)
            cm[r] = fmaxf(cm[r], __shfl_xor(cm[r], off));
    #pragma unroll
    for (int nt = 0; nt < 4; nt++)
        #pragma unroll
        for (int r = 0; r < 4; r++)
            pr[nt][r] = __expf(zl[nt][r] - cm[r]);
    #pragma unroll
    for (int r = 0; r < 4; r++)
        rsum[r] = (pr[0][r] + pr[1][r]) + (pr[2][r] + pr[3][r]);
    #pragma unroll
    for (int off = 1; off < 16; off <<= 1)
        #pragma unroll
        for (int r = 0; r < 4; r++)
            rsum[r] += __shfl_xor(rsum[r], off);
    #pragma unroll
    for (int nt = 0; nt < 4; nt++) {
        int s = nt >> 1, c = (nt & 1) * 16 + n16;
        #pragma unroll
        for (int r = 0; r < 4; r++)
            Pw[s * 640 + (quad * 4 + r) * 40 + c] = f2bf(pr[nt][r]);
    }
    short8 pa0 = *(const short8*)&Pw[0 * 640 + n16 * 40 + quad * 8];
    short8 pa1 = *(const short8*)&Pw[1 * 640 + n16 * 40 + quad * 8];
    f32x4 oacc[4] = {};
    #pragma unroll
    for (int et = 0; et < 4; et++) {
        short8 v0 = *(const short8*)&Vl[(et * 16 + n16) * 64 + sl0];
        short8 v1 = *(const short8*)&Vl[(et * 16 + n16) * 64 + sl1];
        oacc[et] = MFMA16(pa0, v0, oacc[et]);
        oacc[et] = MFMA16(pa1, v1, oacc[et]);
    }
    if (!isSplit) {
        #pragma unroll
        for (int et = 0; et < 4; et++) {
            #pragma unroll
            for (int r = 0; r < 4; r++) {
                float o = oacc[et][r] / rsum[r];
                int l = m0 + quad * 4 + r;
                voutb[(b * 2048 + l) * 512 + h * 64 + et * 16 + n16] = f2bf(o);
            }
        }
        return;
    }
    const int pb = (bh * 32 + chunk) * 64;
    #pragma unroll
    for (int et = 0; et < 4; et++)
        #pragma unroll
        for (int r = 0; r < 4; r++)
            Opart[(pb + w * 16 + quad * 4 + r) * 64 + et * 16 + n16] = oacc[et][r];
    if (n16 == 0) {
        #pragma unroll
        for (int r = 0; r < 4; r++) {
            Mp[pb + iloc + r] = cm[r];
            Lp[pb + iloc + r] = rsum[r];
        }
    }
}

// ---------------------------------------------------------------------------
// Kernel 3: merge 32 partials per (b,h). grid 256 blocks (16 bh x 16 row-
// groups), one wave per row, 64 coalesced cols.  (unchanged from R8)
// ---------------------------------------------------------------------------
__global__ __launch_bounds__(256) void attn31_merge(
    const float* __restrict__ Opart, const float* __restrict__ Mp,
    const float* __restrict__ Lp, unsigned short* __restrict__ voutb)
{
    const int bh = blockIdx.x >> 4, rg = blockIdx.x & 15;
    const int b = bh >> 3, h = bh & 7;
    const int t = threadIdx.x;
    const int row = rg * 4 + (t >> 6), col = t & 63;
    float mv[32];
    float M = -1e30f;
    #pragma unroll
    for (int s = 0; s < 32; s++) {
        mv[s] = Mp[(bh * 32 + s) * 64 + row];
        M = fmaxf(M, mv[s]);
    }
    float L = 0.f, acc = 0.f;
    #pragma unroll 8
    for (int s = 0; s < 32; s++) {
        const float e = __expf(mv[s] - M);
        L += Lp[(bh * 32 + s) * 64 + row] * e;
        acc += Opart[((bh * 32 + s) * 64 + row) * 64 + col] * e;
    }
    voutb[(b * 2048 + 1984 + row) * 512 + h * 64 + col] = f2bf(acc / L);
}

// ---------------------------------------------------------------------------
// Kernel 4: out = voutb(4096x512) @ Wo^T + bo -> fp32.  64x64 tiles, BK=64.
// A (vob bf16) via GLD16; B (Wo fp32) via fused-convert VGPR staging.
// ---------------------------------------------------------------------------
__global__ __launch_bounds__(256) void gemm_out(
    const unsigned short* __restrict__ ab, const float* __restrict__ wo,
    const float* __restrict__ bo, float* __restrict__ out)
{
    const int n0 = blockIdx.x * 64, m0 = blockIdx.y * 64;
    __shared__ unsigned short Al[8 * 512];
    __shared__ unsigned short Bl[8 * 512];
    const int t = threadIdx.x;
    const int lane = t & 63, w = t >> 6;
    const int wrow = (w >> 1) * 32, wcol = (w & 1) * 32;
    const int quad = lane >> 4, n16 = lane & 15;
    const int rA = lane >> 2;
    const int cG = (((lane & 3) ^ ((rA >> 1) & 3))) * 8;
    const int slotq = (quad ^ ((n16 >> 1) & 3)) * 8;
    f32x4 acc[2][2] = {};
    for (int k0 = 0; k0 < 512; k0 += 64) {
        __syncthreads();
        GLD16(&ab[(m0 + w * 16 + rA) * 512 + k0 + cG],      &Al[(w * 2 + 0) * 512]);
        GLD16(&ab[(m0 + w * 16 + rA) * 512 + k0 + 32 + cG], &Al[(w * 2 + 1) * 512]);
        #pragma unroll
        for (int p = 0; p < 2; p++)
            stage_fp32(&wo[(n0 + w * 16 + rA) * 512 + k0 + p * 32 + cG],
                       &Bl[(w * 2 + p) * 512], lane);
        __syncthreads();
        short8 af[2][2], bfr[2][2];
        #pragma unroll
        for (int mi = 0; mi < 2; mi++)
            #pragma unroll
            for (int p = 0; p < 2; p++)
                af[mi][p] = *(const short8*)&Al[((2 * (w >> 1) + mi) * 2 + p) * 512 + n16 * 32 + slotq];
        #pragma unroll
        for (int ni = 0; ni < 2; ni++)
            #pragma unroll
            for (int p = 0; p < 2; p++)
                bfr[ni][p] = *(const short8*)&Bl[((2 * (w & 1) + ni) * 2 + p) * 512 + n16 * 32 + slotq];
        #pragma unroll
        for (int p = 0; p < 2; p++)
            #pragma unroll
            for (int mi = 0; mi < 2; mi++)
                #pragma unroll
                for (int ni = 0; ni < 2; ni++)
                    acc[mi][ni] = MFMA16(af[mi][p], bfr[ni][p], acc[mi][ni]);
    }
    #pragma unroll
    for (int mi = 0; mi < 2; mi++) {
        #pragma unroll
        for (int ni = 0; ni < 2; ni++) {
            const int n = n0 + wcol + ni * 16 + n16;
            const int mb = m0 + wrow + mi * 16 + quad * 4;
            const float bias = bo[n];
            f32x4 v = acc[mi][ni];
            #pragma unroll
            for (int r = 0; r < 4; r++)
                out[(mb + r) * 512 + n] = v[r] + bias;
        }
    }
}

// ---------------------------------------------------------------------------
extern "C" void kernel_launch(void* const* d_in, const int* in_sizes, int n_in,
                              void* d_out, int out_size, void* d_ws, size_t ws_size,
                              hipStream_t stream)
{
    const float* x        = (const float*)d_in[0];
    const float* Wq       = (const float*)d_in[1];
    const float* bq       = (const float*)d_in[2];
    const float* Wk       = (const float*)d_in[3];
    const float* bk       = (const float*)d_in[4];
    const float* Wv       = (const float*)d_in[5];
    const float* bv       = (const float*)d_in[6];
    const float* Wo       = (const float*)d_in[7];
    const float* bo       = (const float*)d_in[8];
    const float* bias_emb = (const float*)d_in[9];

    unsigned short* qb  = (unsigned short*)d_ws;      // (B,H,L,E)  4 MB
    unsigned short* kb  = qb + 2097152;               // (B,H,L,E)  4 MB
    unsigned short* vT  = kb + 2097152;               // (B,H,E,L)  4 MB
    unsigned short* vob = vT + 2097152;               // (B,L,H*E)  4 MB

    float* Opart = (float*)(vob + 2097152);           // 8 MB
    float* Mp    = Opart + 2097152;
    float* Lp    = Mp + 32768;

    hipLaunchKernelGGL(gemm_qkv, dim3(4, 64, 3), dim3(256), 0, stream,
                       x, Wq, Wk, Wv, bq, bk, bv, qb, kb, vT);
    hipLaunchKernelGGL(attn_all, dim3(63, 8, 2), dim3(256), 0, stream,
                       qb, kb, vT, bias_emb, vob, Opart, Mp, Lp);
    hipLaunchKernelGGL(attn31_merge, dim3(256), dim3(256), 0, stream,
                       Opart, Mp, Lp, vob);
    hipLaunchKernelGGL(gemm_out, dim3(8, 64), dim3(256), 0, stream,
                       vob, Wo, bo, (float*)d_out);
}

// Round 11
// 118.079 us; speedup vs baseline: 1.0920x; 1.0920x over previous
//
#include <hip/hip_runtime.h>

typedef __attribute__((ext_vector_type(8))) short short8;
typedef __attribute__((ext_vector_type(4))) float f32x4;
typedef __attribute__((ext_vector_type(4))) unsigned short u16x4;

#define MFMA16(a, b, c) __builtin_amdgcn_mfma_f32_16x16x32_bf16(a, b, c, 0, 0, 0)

// global_load_lds: per-lane 16B from global -> wave-uniform LDS base + lane*16
#define GLD16(gp, lp) __builtin_amdgcn_global_load_lds( \
    (const __attribute__((address_space(1))) unsigned int*)(gp), \
    (__attribute__((address_space(3))) unsigned int*)(lp), 16, 0, 0)

__device__ __forceinline__ unsigned short f2bf(float f) {
    union { float f; unsigned int u; } v; v.f = f;
    unsigned int r = (v.u + 0x7fffu + ((v.u >> 16) & 1u)) >> 16;
    return (unsigned short)r;
}

// ---------------------------------------------------------------------------
// Kernel 1: fp32 -> bf16 convert: x (2097152) then Wq,Wk,Wv,Wo (262144 each)
// (R10 lesson: pre-converting is worth the dispatch — operands are re-read
// 12-64x by the GEMMs; fused fp32 staging doubled traffic and cost +10 us.)
// ---------------------------------------------------------------------------
__global__ __launch_bounds__(256) void convertk(
    const float* __restrict__ x, const float* __restrict__ wq,
    const float* __restrict__ wk, const float* __restrict__ wv,
    const float* __restrict__ wo, unsigned short* __restrict__ xb,
    unsigned short* __restrict__ wb)
{
    int i = (blockIdx.x * 256 + threadIdx.x) * 4;
    const float* src;
    unsigned short* dst;
    if (i < 2097152) { src = x + i; dst = xb + i; }
    else {
        int j = i - 2097152;
        int w = j >> 18;
        int o = j & 262143;
        src = (w == 0 ? wq : w == 1 ? wk : w == 2 ? wv : wo) + o;
        dst = wb + j;
    }
    float4 v = *(const float4*)src;
    u16x4 p;
    p[0] = f2bf(v.x); p[1] = f2bf(v.y); p[2] = f2bf(v.z); p[3] = f2bf(v.w);
    *(u16x4*)dst = p;
}

// ---------------------------------------------------------------------------
// Kernel 2: QKV GEMM, 64x128 tiles, BK=64, swizzled global_load_lds staging,
// fused RoPE epilogue.
// ---------------------------------------------------------------------------
__global__ __launch_bounds__(256) void gemm_qkv(
    const unsigned short* __restrict__ xb, const unsigned short* __restrict__ wb,
    const float* __restrict__ bq, const float* __restrict__ bk,
    const float* __restrict__ bv,
    unsigned short* __restrict__ qb, unsigned short* __restrict__ kb,
    unsigned short* __restrict__ vT)
{
    const int z = blockIdx.z;
    const unsigned short* Wz = wb + z * 262144;
    const int n0 = blockIdx.x * 128, m0 = blockIdx.y * 64;
    __shared__ unsigned short Al[8 * 512];    // 8 KB
    __shared__ unsigned short Bl[16 * 512];   // 16 KB
    const int t = threadIdx.x;
    const int lane = t & 63, w = t >> 6;
    const int wrow = (w >> 1) * 32, wcol = (w & 1) * 64;
    const int quad = lane >> 4, n16 = lane & 15;
    const int rA = lane >> 2;
    const int cG = (((lane & 3) ^ ((rA >> 1) & 3))) * 8;
    const int slotq = (quad ^ ((n16 >> 1) & 3)) * 8;
    f32x4 acc[2][4] = {};
    for (int k0 = 0; k0 < 512; k0 += 64) {
        __syncthreads();
        GLD16(&xb[(m0 + w * 16 + rA) * 512 + k0 + cG],      &Al[(w * 2 + 0) * 512]);
        GLD16(&xb[(m0 + w * 16 + rA) * 512 + k0 + 32 + cG], &Al[(w * 2 + 1) * 512]);
        GLD16(&Wz[(n0 + w * 32 + rA) * 512 + k0 + cG],           &Bl[(w * 4 + 0) * 512]);
        GLD16(&Wz[(n0 + w * 32 + rA) * 512 + k0 + 32 + cG],      &Bl[(w * 4 + 1) * 512]);
        GLD16(&Wz[(n0 + w * 32 + 16 + rA) * 512 + k0 + cG],      &Bl[(w * 4 + 2) * 512]);
        GLD16(&Wz[(n0 + w * 32 + 16 + rA) * 512 + k0 + 32 + cG], &Bl[(w * 4 + 3) * 512]);
        __syncthreads();
        short8 af[2][2], bfr[4][2];
        #pragma unroll
        for (int mi = 0; mi < 2; mi++)
            #pragma unroll
            for (int p = 0; p < 2; p++)
                af[mi][p] = *(const short8*)&Al[((2 * (w >> 1) + mi) * 2 + p) * 512 + n16 * 32 + slotq];
        #pragma unroll
        for (int ni = 0; ni < 4; ni++)
            #pragma unroll
            for (int p = 0; p < 2; p++)
                bfr[ni][p] = *(const short8*)&Bl[((4 * (w & 1) + ni) * 2 + p) * 512 + n16 * 32 + slotq];
        #pragma unroll
        for (int p = 0; p < 2; p++)
            #pragma unroll
            for (int mi = 0; mi < 2; mi++)
                #pragma unroll
                for (int ni = 0; ni < 4; ni++)
                    acc[mi][ni] = MFMA16(af[mi][p], bfr[ni][p], acc[mi][ni]);
    }
    const float* bias_p = (z == 0) ? bq : (z == 1) ? bk : bv;
    unsigned short* dst01 = (z == 0) ? qb : kb;
    #pragma unroll
    for (int mi = 0; mi < 2; mi++) {
        #pragma unroll
        for (int ni = 0; ni < 4; ni++) {
            const int n = n0 + wcol + ni * 16 + n16;
            const int mb = m0 + wrow + mi * 16 + quad * 4;
            const float bias = bias_p[n];
            const int h = n >> 6;
            const int e_lo = ni * 16 + n16;
            f32x4 v = acc[mi][ni];
            if (z < 2) {
                float vr[4];
                #pragma unroll
                for (int r = 0; r < 4; r++) vr[r] = v[r] + bias;
                if (ni < 2) {   // e < 32: RoPE
                    const int j = e_lo >> 1;
                    const float theta = exp2f(-(float)j * 0.8304820237218405f);
                    #pragma unroll
                    for (int r = 0; r < 4; r++) {
                        int l = (mb + r) & 2047;
                        float s, c;
                        __sincosf((float)l * theta, &s, &c);
                        float p = __shfl_xor(vr[r], 1);
                        vr[r] = (e_lo & 1) ? (c * vr[r] + s * p) : (c * vr[r] - s * p);
                    }
                }
                #pragma unroll
                for (int r = 0; r < 4; r++) {
                    int m = mb + r, b = m >> 11, l = m & 2047;
                    dst01[((b * 8 + h) * 2048 + l) * 64 + e_lo] = f2bf(vr[r]);
                }
            } else {
                int b = mb >> 11, l = mb & 2047;
                u16x4 pk;
                #pragma unroll
                for (int r = 0; r < 4; r++) pk[r] = f2bf(v[r] + bias);
                *(u16x4*)&vT[((b * 8 + h) * 64 + e_lo) * 2048 + l] = pk;
            }
        }
    }
}

// ---------------------------------------------------------------------------
// Kernel 3: attention. grid (63, 8, 2), single chunk per block.
// K/V staged once per block into LDS (waves 0-1 K, 2-3 V), XOR swizzle.
// ---------------------------------------------------------------------------
__global__ __launch_bounds__(256) void attn_all(
    const unsigned short* __restrict__ qb, const unsigned short* __restrict__ kb,
    const unsigned short* __restrict__ vT, const float* __restrict__ bias_emb,
    unsigned short* __restrict__ voutb,
    float* __restrict__ Opart, float* __restrict__ Mp, float* __restrict__ Lp)
{
    const int xid = blockIdx.x, h = blockIdx.y, b = blockIdx.z;
    const int t = threadIdx.x, lane = t & 63, w = t >> 6;
    const int quad = lane >> 4, n16 = lane & 15;
    const int bh = b * 8 + h;
    __shared__ unsigned short Kl[64 * 64];
    __shared__ unsigned short Vl[64 * 64];
    __shared__ unsigned short Pl[4 * 1280];
    unsigned short* Pw = &Pl[w * 1280];
    const int qoff = bh * 2048 * 64;
    const float scale = 0.125f;
    const bool isSplit = (xid >= 31);
    const int var = isSplit ? 31 : xid;
    const int chunk = isSplit ? (xid - 31) : xid;
    const bool causal = (chunk == var);
    const float biasv = causal ? bias_emb[8 + h] : bias_emb[h];
    const int m0 = var * 64 + w * 16;
    const int j0 = chunk * 64;
    const int iloc = w * 16 + quad * 4;

    {
        const int half = (w & 1) * 32;
        const int rl = lane >> 3;
        const int gblk = ((lane & 7) ^ (rl & 7)) * 8;
        if (w < 2) {
            #pragma unroll
            for (int n = 0; n < 4; n++) {
                const int row = half + n * 8 + rl;
                GLD16(&kb[qoff + (j0 + row) * 64 + gblk], &Kl[(half + n * 8) * 64]);
            }
        } else {
            #pragma unroll
            for (int n = 0; n < 4; n++) {
                const int row = half + n * 8 + rl;
                GLD16(&vT[(bh * 64 + row) * 2048 + j0 + gblk], &Vl[(half + n * 8) * 64]);
            }
        }
    }
    short8 aq0 = *(const short8*)&qb[qoff + (m0 + n16) * 64 + quad * 8];
    short8 aq1 = *(const short8*)&qb[qoff + (m0 + n16) * 64 + 32 + quad * 8];
    __syncthreads();

    const int sl0 = (quad ^ (n16 & 7)) * 8;
    const int sl1 = (((quad + 4) ^ (n16 & 7))) * 8;
    f32x4 sc[4];
    #pragma unroll
    for (int nt = 0; nt < 4; nt++) {
        short8 k0f = *(const short8*)&Kl[(nt * 16 + n16) * 64 + sl0];
        short8 k1f = *(const short8*)&Kl[(nt * 16 + n16) * 64 + sl1];
        f32x4 s = {};
        s = MFMA16(aq0, k0f, s);
        s = MFMA16(aq1, k1f, s);
        sc[nt] = s;
    }
    float zl[4][4];
    #pragma unroll
    for (int nt = 0; nt < 4; nt++) {
        int jloc = nt * 16 + n16;
        #pragma unroll
        for (int r = 0; r < 4; r++) {
            float zz = scale * (sc[nt][r] + biasv);
            if (causal && jloc > iloc + r) zz = -1e30f;
            zl[nt][r] = zz;
        }
    }
    float cm[4], rsum[4], pr[4][4];
    #pragma unroll
    for (int r = 0; r < 4; r++)
        cm[r] = fmaxf(fmaxf(zl[0][r], zl[1][r]), fmaxf(zl[2][r], zl[3][r]));
    #pragma unroll
    for (int off = 1; off < 16; off <<= 1)
        #pragma unroll
        for (int r = 0; r < 4; r++)
            cm[r] = fmaxf(cm[r], __shfl_xor(cm[r], off));
    #pragma unroll
    for (int nt = 0; nt < 4; nt++)
        #pragma unroll
        for (int r = 0; r < 4; r++)
            pr[nt][r] = __expf(zl[nt][r] - cm[r]);
    #pragma unroll
    for (int r = 0; r < 4; r++)
        rsum[r] = (pr[0][r] + pr[1][r]) + (pr[2][r] + pr[3][r]);
    #pragma unroll
    for (int off = 1; off < 16; off <<= 1)
        #pragma unroll
        for (int r = 0; r < 4; r++)
            rsum[r] += __shfl_xor(rsum[r], off);
    #pragma unroll
    for (int nt = 0; nt < 4; nt++) {
        int s = nt >> 1, c = (nt & 1) * 16 + n16;
        #pragma unroll
        for (int r = 0; r < 4; r++)
            Pw[s * 640 + (quad * 4 + r) * 40 + c] = f2bf(pr[nt][r]);
    }
    short8 pa0 = *(const short8*)&Pw[0 * 640 + n16 * 40 + quad * 8];
    short8 pa1 = *(const short8*)&Pw[1 * 640 + n16 * 40 + quad * 8];
    f32x4 oacc[4] = {};
    #pragma unroll
    for (int et = 0; et < 4; et++) {
        short8 v0 = *(const short8*)&Vl[(et * 16 + n16) * 64 + sl0];
        short8 v1 = *(const short8*)&Vl[(et * 16 + n16) * 64 + sl1];
        oacc[et] = MFMA16(pa0, v0, oacc[et]);
        oacc[et] = MFMA16(pa1, v1, oacc[et]);
    }
    if (!isSplit) {
        #pragma unroll
        for (int et = 0; et < 4; et++) {
            #pragma unroll
            for (int r = 0; r < 4; r++) {
                float o = oacc[et][r] / rsum[r];
                int l = m0 + quad * 4 + r;
                voutb[(b * 2048 + l) * 512 + h * 64 + et * 16 + n16] = f2bf(o);
            }
        }
        return;
    }
    const int pb = (bh * 32 + chunk) * 64;
    #pragma unroll
    for (int et = 0; et < 4; et++)
        #pragma unroll
        for (int r = 0; r < 4; r++)
            Opart[(pb + w * 16 + quad * 4 + r) * 64 + et * 16 + n16] = oacc[et][r];
    if (n16 == 0) {
        #pragma unroll
        for (int r = 0; r < 4; r++) {
            Mp[pb + iloc + r] = cm[r];
            Lp[pb + iloc + r] = rsum[r];
        }
    }
}

// ---------------------------------------------------------------------------
// Kernel 4: merge 32 partials per (b,h). grid 256 blocks (16 bh x 16 row-
// groups), one wave per row, 64 coalesced cols.
// ---------------------------------------------------------------------------
__global__ __launch_bounds__(256) void attn31_merge(
    const float* __restrict__ Opart, const float* __restrict__ Mp,
    const float* __restrict__ Lp, unsigned short* __restrict__ voutb)
{
    const int bh = blockIdx.x >> 4, rg = blockIdx.x & 15;
    const int b = bh >> 3, h = bh & 7;
    const int t = threadIdx.x;
    const int row = rg * 4 + (t >> 6), col = t & 63;
    float mv[32];
    float M = -1e30f;
    #pragma unroll
    for (int s = 0; s < 32; s++) {
        mv[s] = Mp[(bh * 32 + s) * 64 + row];
        M = fmaxf(M, mv[s]);
    }
    float L = 0.f, acc = 0.f;
    #pragma unroll 8
    for (int s = 0; s < 32; s++) {
        const float e = __expf(mv[s] - M);
        L += Lp[(bh * 32 + s) * 64 + row] * e;
        acc += Opart[((bh * 32 + s) * 64 + row) * 64 + col] * e;
    }
    voutb[(b * 2048 + 1984 + row) * 512 + h * 64 + col] = f2bf(acc / L);
}

// ---------------------------------------------------------------------------
// Kernel 5: out = voutb(4096x512) @ Wo^T + bo -> fp32.  64x64 tiles, BK=64.
// ---------------------------------------------------------------------------
__global__ __launch_bounds__(256) void gemm_out(
    const unsigned short* __restrict__ ab, const unsigned short* __restrict__ wo,
    const float* __restrict__ bo, float* __restrict__ out)
{
    const int n0 = blockIdx.x * 64, m0 = blockIdx.y * 64;
    __shared__ unsigned short Al[8 * 512];
    __shared__ unsigned short Bl[8 * 512];
    const int t = threadIdx.x;
    const int lane = t & 63, w = t >> 6;
    const int wrow = (w >> 1) * 32, wcol = (w & 1) * 32;
    const int quad = lane >> 4, n16 = lane & 15;
    const int rA = lane >> 2;
    const int cG = (((lane & 3) ^ ((rA >> 1) & 3))) * 8;
    const int slotq = (quad ^ ((n16 >> 1) & 3)) * 8;
    f32x4 acc[2][2] = {};
    for (int k0 = 0; k0 < 512; k0 += 64) {
        __syncthreads();
        GLD16(&ab[(m0 + w * 16 + rA) * 512 + k0 + cG],      &Al[(w * 2 + 0) * 512]);
        GLD16(&ab[(m0 + w * 16 + rA) * 512 + k0 + 32 + cG], &Al[(w * 2 + 1) * 512]);
        GLD16(&wo[(n0 + w * 16 + rA) * 512 + k0 + cG],      &Bl[(w * 2 + 0) * 512]);
        GLD16(&wo[(n0 + w * 16 + rA) * 512 + k0 + 32 + cG], &Bl[(w * 2 + 1) * 512]);
        __syncthreads();
        short8 af[2][2], bfr[2][2];
        #pragma unroll
        for (int mi = 0; mi < 2; mi++)
            #pragma unroll
            for (int p = 0; p < 2; p++)
                af[mi][p] = *(const short8*)&Al[((2 * (w >> 1) + mi) * 2 + p) * 512 + n16 * 32 + slotq];
        #pragma unroll
        for (int ni = 0; ni < 2; ni++)
            #pragma unroll
            for (int p = 0; p < 2; p++)
                bfr[ni][p] = *(const short8*)&Bl[((2 * (w & 1) + ni) * 2 + p) * 512 + n16 * 32 + slotq];
        #pragma unroll
        for (int p = 0; p < 2; p++)
            #pragma unroll
            for (int mi = 0; mi < 2; mi++)
                #pragma unroll
                for (int ni = 0; ni < 2; ni++)
                    acc[mi][ni] = MFMA16(af[mi][p], bfr[ni][p], acc[mi][ni]);
    }
    #pragma unroll
    for (int mi = 0; mi < 2; mi++) {
        #pragma unroll
        for (int ni = 0; ni < 2; ni++) {
            const int n = n0 + wcol + ni * 16 + n16;
            const int mb = m0 + wrow + mi * 16 + quad * 4;
            const float bias = bo[n];
            f32x4 v = acc[mi][ni];
            #pragma unroll
            for (int r = 0; r < 4; r++)
                out[(mb + r) * 512 + n] = v[r] + bias;
        }
    }
}

// ---------------------------------------------------------------------------
extern "C" void kernel_launch(void* const* d_in, const int* in_sizes, int n_in,
                              void* d_out, int out_size, void* d_ws, size_t ws_size,
                              hipStream_t stream)
{
    const float* x        = (const float*)d_in[0];
    const float* Wq       = (const float*)d_in[1];
    const float* bq       = (const float*)d_in[2];
    const float* Wk       = (const float*)d_in[3];
    const float* bk       = (const float*)d_in[4];
    const float* Wv       = (const float*)d_in[5];
    const float* bv       = (const float*)d_in[6];
    const float* Wo       = (const float*)d_in[7];
    const float* bo       = (const float*)d_in[8];
    const float* bias_emb = (const float*)d_in[9];

    unsigned short* xb  = (unsigned short*)d_ws;      // 2097152 elems
    unsigned short* wb  = xb + 2097152;               // 4 * 262144
    unsigned short* qb  = wb + 1048576;               // (B,H,L,E)
    unsigned short* kb  = qb + 2097152;               // (B,H,L,E)
    unsigned short* vT  = kb + 2097152;               // (B,H,E,L)
    unsigned short* vob = vT + 2097152;               // (B,L,H*E)

    float* Opart = (float*)(vob + 2097152);           // 8 MB
    float* Mp    = Opart + 2097152;
    float* Lp    = Mp + 32768;

    hipLaunchKernelGGL(convertk, dim3(3072), dim3(256), 0, stream,
                       x, Wq, Wk, Wv, Wo, xb, wb);
    hipLaunchKernelGGL(gemm_qkv, dim3(4, 64, 3), dim3(256), 0, stream,
                       xb, wb, bq, bk, bv, qb, kb, vT);
    hipLaunchKernelGGL(attn_all, dim3(63, 8, 2), dim3(256), 0, stream,
                       qb, kb, vT, bias_emb, vob, Opart, Mp, Lp);
    hipLaunchKernelGGL(attn31_merge, dim3(256), dim3(256), 0, stream,
                       Opart, Mp, Lp, vob);
    hipLaunchKernelGGL(gemm_out, dim3(8, 64), dim3(256), 0, stream,
                       vob, wb + 3 * 262144, bo, (float*)d_out);
}